// Round 1
// baseline (433.226 us; speedup 1.0000x reference)
//
#include <hip/hip_runtime.h>
#include <stdint.h>

#define D 2048
#define V 4096
#define TINYF 1.17549435e-38f

// RNG scheme: 1 = partitionable threefry (JAX >= 0.4.30 default), XOR-fold of the
// two 32-bit output words.  0 = legacy split-half counter mode.  2/3 = partitionable
// taking only word0 / word1.  Fallback ladder if output-0 indices mismatch.
#ifndef RNG_SCHEME
#define RNG_SCHEME 1
#endif

__device__ __forceinline__ void tf_block(uint32_t k0, uint32_t k1, uint32_t x0, uint32_t x1,
                                         uint32_t& o0, uint32_t& o1) {
  uint32_t ks2 = k0 ^ k1 ^ 0x1BD11BDAu;
  uint32_t ks[3] = {k0, k1, ks2};
  x0 += k0; x1 += k1;
  const uint32_t rotA[4] = {13u, 15u, 26u, 6u};
  const uint32_t rotB[4] = {17u, 29u, 16u, 24u};
#pragma unroll
  for (int i = 0; i < 5; ++i) {
    const uint32_t* rot = (i & 1) ? rotB : rotA;
#pragma unroll
    for (int j = 0; j < 4; ++j) {
      uint32_t r = rot[j];
      x0 += x1;
      x1 = (x1 << r) | (x1 >> (32u - r));
      x1 ^= x0;
    }
    x0 += ks[(i + 1) % 3];
    x1 += ks[(i + 2) % 3] + (uint32_t)(i + 1);
  }
  o0 = x0; o1 = x1;
}

__device__ __forceinline__ uint32_t random_bits_at(uint32_t k1, uint32_t k2, int i, int N) {
  uint32_t o0, o1;
#if RNG_SCHEME == 0
  int M = N + (N & 1);
  int H = M >> 1;
  if (i < H) {
    uint32_t x1 = (H + i < N) ? (uint32_t)(H + i) : 0u;
    tf_block(k1, k2, (uint32_t)i, x1, o0, o1);
    return o0;
  } else {
    tf_block(k1, k2, (uint32_t)(i - H), (uint32_t)i, o0, o1);
    return o1;
  }
#elif RNG_SCHEME == 1
  tf_block(k1, k2, 0u, (uint32_t)i, o0, o1);
  return o0 ^ o1;
#elif RNG_SCHEME == 2
  tf_block(k1, k2, 0u, (uint32_t)i, o0, o1);
  return o0;
#else
  tf_block(k1, k2, 0u, (uint32_t)i, o0, o1);
  return o1;
#endif
}

__global__ void zero_kernel(float* __restrict__ p, int n) {
  int i = blockIdx.x * 256 + threadIdx.x;
  if (i < n) p[i] = 0.f;
}

// One wave (64 lanes) per output row j; 4 waves/block; grid = D/4 blocks.
// Computes all 4 gate dots (ih + hh) for its j, then the LSTM elementwise update.
__global__ void lstm_cell_kernel(const float* __restrict__ w_ih, const float* __restrict__ w_hh,
                                 const float* __restrict__ b_ih, const float* __restrict__ b_hh,
                                 const float* __restrict__ x_base, const int* __restrict__ x_idx,
                                 const float* __restrict__ h_in, const float* __restrict__ c_in,
                                 float* __restrict__ h_out, float* __restrict__ c_out,
                                 float* __restrict__ c_copy) {
  __shared__ float xs[D];
  __shared__ float hs[D];
  int tid = threadIdx.x;
  const float* x = x_base;
  if (x_idx) x += (size_t)(*x_idx) * D;
  for (int i = tid; i < D; i += 256) { xs[i] = x[i]; hs[i] = h_in[i]; }
  __syncthreads();
  int wave = tid >> 6, lane = tid & 63;
  int j = blockIdx.x * 4 + wave;
  float gv[4];
#pragma unroll
  for (int m = 0; m < 4; ++m) {
    const float* rih = w_ih + (size_t)(m * D + j) * D;
    const float* rhh = w_hh + (size_t)(m * D + j) * D;
    float a = 0.f;
#pragma unroll
    for (int k = lane * 4; k < D; k += 256) {
      float4 wv = *(const float4*)(rih + k);
      float4 xv = *(const float4*)(xs + k);
      a += wv.x * xv.x + wv.y * xv.y + wv.z * xv.z + wv.w * xv.w;
      float4 wh = *(const float4*)(rhh + k);
      float4 hv = *(const float4*)(hs + k);
      a += wh.x * hv.x + wh.y * hv.y + wh.z * hv.z + wh.w * hv.w;
    }
#pragma unroll
    for (int off = 32; off > 0; off >>= 1) a += __shfl_down(a, off, 64);
    gv[m] = a + b_ih[m * D + j] + b_hh[m * D + j];
  }
  if (lane == 0) {
    float ig = 1.f / (1.f + expf(-gv[0]));
    float fg = 1.f / (1.f + expf(-gv[1]));
    float gg = tanhf(gv[2]);
    float og = 1.f / (1.f + expf(-gv[3]));
    float cn = fg * c_in[j] + ig * gg;
    float hn = og * tanhf(cn);
    c_out[j] = cn;
    h_out[j] = hn;
    if (c_copy) c_copy[j] = cn;
  }
}

// y[row] = dot(W[row,:], v) + b[row]; one wave per row, 4 rows per block.
__global__ void gemv_kernel(const float* __restrict__ W, const float* __restrict__ b,
                            const float* __restrict__ v, float* __restrict__ y, int R) {
  __shared__ float vs[D];
  int tid = threadIdx.x;
  for (int i = tid; i < D; i += 256) vs[i] = v[i];
  __syncthreads();
  int wave = tid >> 6, lane = tid & 63;
  int row = blockIdx.x * 4 + wave;
  if (row >= R) return;
  const float* wr = W + (size_t)row * D;
  float acc = 0.f;
#pragma unroll
  for (int k = lane * 4; k < D; k += 256) {
    float4 wv = *(const float4*)(wr + k);
    float4 xv = *(const float4*)(vs + k);
    acc += wv.x * xv.x + wv.y * xv.y + wv.z * xv.z + wv.w * xv.w;
  }
#pragma unroll
  for (int off = 32; off > 0; off >>= 1) acc += __shfl_down(acc, off, 64);
  if (lane == 0) y[row] = acc + (b ? b[row] : 0.f);
}

// logit[t] = sum_k tanh(qb[k] + all_cw[t*D+k]) * lin3_w[k] + lin3_b[0]; block per t.
__global__ void attn_logits_kernel(const float* __restrict__ qb, const float* __restrict__ all_cw,
                                   const float* __restrict__ lin3_w, const float* __restrict__ lin3_b,
                                   float* __restrict__ out) {
  __shared__ float red[256];
  int t = blockIdx.x, tid = threadIdx.x;
  const float* cw = all_cw + (size_t)t * D;
  float s = 0.f;
  for (int k = tid; k < D; k += 256) s += tanhf(qb[k] + cw[k]) * lin3_w[k];
  red[tid] = s;
  __syncthreads();
  for (int st = 128; st > 0; st >>= 1) {
    if (tid < st) red[tid] += red[tid + st];
    __syncthreads();
  }
  if (tid == 0) out[t] = red[0] + lin3_b[0];
}

// Single-block sampler: log_softmax stats + threefry gumbel argmax (exact JAX semantics).
__global__ void sample_kernel(const float* __restrict__ logits, int N, int step,
                              float* __restrict__ out_arc, float* __restrict__ out_ent,
                              float* __restrict__ out_lp, int* __restrict__ sel_out) {
  __shared__ float sval[1024];
  __shared__ int sidx[1024];
  int tid = threadIdx.x;
  // fold_in(key(42), step): one threefry block over (0, step) with key (0,42)
  uint32_t k1, k2;
  tf_block(0u, 42u, 0u, (uint32_t)step, k1, k2);
  // max
  float lmax = -INFINITY;
  for (int i = tid; i < N; i += 1024) lmax = fmaxf(lmax, logits[i]);
  sval[tid] = lmax; __syncthreads();
  for (int s = 512; s > 0; s >>= 1) { if (tid < s) sval[tid] = fmaxf(sval[tid], sval[tid + s]); __syncthreads(); }
  float smax = sval[0]; __syncthreads();
  // sum exp
  float lsum = 0.f;
  for (int i = tid; i < N; i += 1024) lsum += expf(logits[i] - smax);
  sval[tid] = lsum; __syncthreads();
  for (int s = 512; s > 0; s >>= 1) { if (tid < s) sval[tid] += sval[tid + s]; __syncthreads(); }
  float L = logf(sval[0]); __syncthreads();
  // entropy
  float lent = 0.f;
  for (int i = tid; i < N; i += 1024) { float lp = logits[i] - smax - L; lent -= lp * expf(lp); }
  sval[tid] = lent; __syncthreads();
  for (int s = 512; s > 0; s >>= 1) { if (tid < s) sval[tid] += sval[tid + s]; __syncthreads(); }
  float ent = sval[0]; __syncthreads();
  // gumbel argmax (first-index tie-break, matching jnp.argmax)
  float bv = -INFINITY;
  int bi = 0x7FFFFFFF;
  for (int i = tid; i < N; i += 1024) {
    uint32_t bits = random_bits_at(k1, k2, i, N);
    float u = __uint_as_float((bits >> 9) | 0x3F800000u) - 1.0f;
    u = fmaxf(TINYF, u + TINYF);   // floats*(1-tiny)+tiny with (1-tiny)==1 in f32
    float g = -logf(-logf(u));
    float sc = g + logits[i];
    if (sc > bv || (sc == bv && i < bi)) { bv = sc; bi = i; }
  }
  sval[tid] = bv; sidx[tid] = bi; __syncthreads();
  for (int s = 512; s > 0; s >>= 1) {
    if (tid < s) {
      float ov = sval[tid + s]; int oi = sidx[tid + s];
      if (ov > sval[tid] || (ov == sval[tid] && oi < sidx[tid])) { sval[tid] = ov; sidx[tid] = oi; }
    }
    __syncthreads();
  }
  if (tid == 0) {
    int idx = sidx[0];
    *out_arc = (float)idx;
    *out_ent = ent;
    *out_lp = logits[idx] - smax - L;
    *sel_out = idx;
  }
}

extern "C" void kernel_launch(void* const* d_in, const int* in_sizes, int n_in,
                              void* d_out, int out_size, void* d_ws, size_t ws_size,
                              hipStream_t stream) {
  const float* emb0   = (const float*)d_in[0];
  const float* w_ih   = (const float*)d_in[1];
  const float* w_hh   = (const float*)d_in[2];
  const float* b_ih   = (const float*)d_in[3];
  const float* b_hh   = (const float*)d_in[4];
  const float* lin1_w = (const float*)d_in[5];
  const float* lin1_b = (const float*)d_in[6];
  const float* lin2_w = (const float*)d_in[7];
  const float* lin2_b = (const float*)d_in[8];
  const float* lin3_w = (const float*)d_in[9];
  const float* lin3_b = (const float*)d_in[10];
  const float* dec_w  = (const float*)d_in[11];
  const float* dec_b  = (const float*)d_in[12];
  const float* embt   = (const float*)d_in[13];

  float* out = (float*)d_out;  // [0..8]=arc (as float), [9..17]=entropy, [18..26]=log_probs
  float* ws = (float*)d_ws;
  float* hA     = ws;                 // D
  float* cA     = ws + D;             // D
  float* hB     = ws + 2 * D;         // D
  float* cB     = ws + 3 * D;         // D
  float* all_c  = ws + 4 * D;         // 4*D
  float* all_cw = ws + 8 * D;         // 4*D
  float* qb     = ws + 12 * D;        // D
  float* logits = ws + 13 * D;        // V (=2*D)
  float* slog   = ws + 15 * D;        // 4 small logits
  int* sel_skip = (int*)(ws + 15 * D + 8);
  int* sel_func = (int*)(ws + 15 * D + 9);

  // h, c = 0 (pair A); all later buffers are written before read within this call
  zero_kernel<<<(2 * D + 255) / 256, 256, 0, stream>>>(hA, 2 * D);

  float* h_in = hA; float* c_in = cA; float* h_out = hB; float* c_out = cB;
  int step = 0;
  for (int layer = 0; layer < 4; ++layer) {
    // ---- first cell of layer ----
    const float* xb; const int* xi;
    if (layer == 0) { xb = emb0; xi = nullptr; }
    else            { xb = embt + (size_t)(layer - 1) * V * D; xi = sel_func; }
    lstm_cell_kernel<<<D / 4, 256, 0, stream>>>(w_ih, w_hh, b_ih, b_hh, xb, xi,
                                                h_in, c_in, h_out, c_out, all_c + (size_t)layer * D);
    { float* t = h_in; h_in = h_out; h_out = t; t = c_in; c_in = c_out; c_out = t; }
    // lin1 -> all_cw[layer], lin2 -> qb
    gemv_kernel<<<D / 4, 256, 0, stream>>>(lin1_w, lin1_b, c_in, all_cw + (size_t)layer * D, D);
    gemv_kernel<<<D / 4, 256, 0, stream>>>(lin2_w, lin2_b, c_in, qb, D);
    attn_logits_kernel<<<layer + 1, 256, 0, stream>>>(qb, all_cw, lin3_w, lin3_b, slog);
    sample_kernel<<<1, 1024, 0, stream>>>(slog, layer + 1, step,
                                          out + step, out + 9 + step, out + 18 + step, sel_skip);
    step++;
    // ---- second cell of layer: input = all_c[skip_idx] ----
    lstm_cell_kernel<<<D / 4, 256, 0, stream>>>(w_ih, w_hh, b_ih, b_hh, all_c, sel_skip,
                                                h_in, c_in, h_out, c_out, nullptr);
    { float* t = h_in; h_in = h_out; h_out = t; t = c_in; c_in = c_out; c_out = t; }
    // decoder logits
    gemv_kernel<<<V / 4, 256, 0, stream>>>(dec_w + (size_t)layer * V * D, dec_b + (size_t)layer * V,
                                           c_in, logits, V);
    sample_kernel<<<1, 1024, 0, stream>>>(logits, V, step,
                                          out + step, out + 9 + step, out + 18 + step, sel_func);
    step++;
  }
  // ---- final cell + decode ----
  lstm_cell_kernel<<<D / 4, 256, 0, stream>>>(w_ih, w_hh, b_ih, b_hh, embt + (size_t)3 * V * D, sel_func,
                                              h_in, c_in, h_out, c_out, nullptr);
  { float* t = h_in; h_in = h_out; h_out = t; t = c_in; c_in = c_out; c_out = t; }
  gemv_kernel<<<V / 4, 256, 0, stream>>>(dec_w + (size_t)4 * V * D, dec_b + (size_t)4 * V,
                                         c_in, logits, V);
  sample_kernel<<<1, 1024, 0, stream>>>(logits, V, step,
                                        out + step, out + 9 + step, out + 18 + step, sel_func);
}